// Round 4
// baseline (454.298 us; speedup 1.0000x reference)
//
#include <hip/hip_runtime.h>
#include <hip/hip_bf16.h>
#include <hip/hip_fp16.h>
#include <hip/hip_cooperative_groups.h>
#include <stdint.h>

namespace cg = cooperative_groups;

// out[e] = sum_d |nodes[r[e]][d] - nodes[c[e]][d]| * w[d] + b[0]
// E = 600000, D = 128, N_OUT = 1.
//
// R1: fp32 gather, 85 us (miss-path bound, FETCH 287 MB).
// R2: fp16 table, 42 us gather (FETCH 132 MB @ 3.1 TB/s miss path).
// R3/R4: ILP + packed fdot2: neutral -> not VALU, not MLP.
// R5: dim-partitioned XCD-pinned slices: FETCH 31 MB (L2-resident proven!)
//     but gather 58 us: 19.2M line-requests (rp[0]/rp[1] = 2 instrs to the
//     SAME 64B line => double-requested), 1.23 GB L2->L1 @ ~21 TB/s.
//     3-kernel launch overhead also grew (~39 us slack vs ~2 at 1 kernel).
// R6 (this):
//   a) pair-lane gather: 2 lanes per (edge,dblk), lane h loads the h-th 16B
//      half of the node's 32B chunk -> same-line lanes coalesce into ONE
//      request per endpoint -> 9.6M requests / 614 MB line traffic (half R5).
//   b) fuse all 3 passes into one cooperative kernel (2x grid.sync()) ->
//      one dispatch, no inter-kernel gaps. 1024 blocks co-resident
//      (launch_bounds(256,4) => <=128 VGPR => 4 blocks/CU).

#define D_FEAT 128
#define DBLK   8      // dim blocks (== XCD count)
#define DPB    16     // halves per node per slice (32 B)
#define COOP_GRID  1024
#define COOP_BLOCK 256

typedef _Float16 h2v __attribute__((ext_vector_type(2)));

// ---- packed abs-diff dot: acc += dot(|a-b|, w) over 2 halves ----
__device__ __forceinline__ float absdot(uint32_t a, uint32_t b, uint32_t w,
                                        float acc)
{
#if __has_builtin(__builtin_amdgcn_fdot2)
    const h2v av = __builtin_bit_cast(h2v, a);
    const h2v bv = __builtin_bit_cast(h2v, b);
    const h2v d  = av - bv;                                   // v_pk_sub_f16
    const uint32_t ad = __builtin_bit_cast(uint32_t, d) & 0x7FFF7FFFu;
    return __builtin_amdgcn_fdot2(__builtin_bit_cast(h2v, ad),
                                  __builtin_bit_cast(h2v, w), acc, false);
#else
    const float2 x = __half22float2(__builtin_bit_cast(__half2, a));
    const float2 y = __half22float2(__builtin_bit_cast(__half2, b));
    const float2 ww = __half22float2(__builtin_bit_cast(__half2, w));
    return acc + fabsf(x.x - y.x) * ww.x + fabsf(x.y - y.y) * ww.y;
#endif
}

// ---- phase-1 item: node n, dim-block k -> convert 16 f32 to 16 f16 ----
__device__ __forceinline__ void conv_item(int t, const float* __restrict__ src,
                                          __half* __restrict__ tbl2,
                                          int n_nodes)
{
    const int n = t >> 3;
    const int k = t & (DBLK - 1);
    const float4* s = (const float4*)(src + (size_t)n * D_FEAT + k * DPB);
    const float4 f0 = s[0], f1 = s[1], f2 = s[2], f3 = s[3];
    uint4 p0, p1;
    __half2* h0 = (__half2*)&p0;
    __half2* h1 = (__half2*)&p1;
    h0[0] = __floats2half2_rn(f0.x, f0.y);
    h0[1] = __floats2half2_rn(f0.z, f0.w);
    h0[2] = __floats2half2_rn(f1.x, f1.y);
    h0[3] = __floats2half2_rn(f1.z, f1.w);
    h1[0] = __floats2half2_rn(f2.x, f2.y);
    h1[1] = __floats2half2_rn(f2.z, f2.w);
    h1[2] = __floats2half2_rn(f3.x, f3.y);
    h1[3] = __floats2half2_rn(f3.z, f3.w);
    uint4* d = (uint4*)(tbl2 + ((size_t)k * n_nodes + n) * DPB);
    d[0] = p0;
    d[1] = p1;
}

__device__ __forceinline__ void conv_w(const float* __restrict__ w,
                                       __half* __restrict__ wh)
{
    // caller: blockIdx.x==0 && threadIdx.x < 16
    const float4* s = (const float4*)w + 2 * (size_t)threadIdx.x;
    const float4 a = s[0];
    const float4 c = s[1];
    float4 packed;
    ((__half2*)&packed)[0] = __floats2half2_rn(a.x, a.y);
    ((__half2*)&packed)[1] = __floats2half2_rn(a.z, a.w);
    ((__half2*)&packed)[2] = __floats2half2_rn(c.x, c.y);
    ((__half2*)&packed)[3] = __floats2half2_rn(c.z, c.w);
    ((float4*)wh)[threadIdx.x] = packed;
}

// ---- phase-2 core: one (edge, kb, h) pair-lane item -> partial sum ----
__device__ __forceinline__ float pair_sum(const char* __restrict__ sbase,
                                          const uint4 wv, int r, int c, int off16)
{
    const uint4 a = *(const uint4*)(sbase + (size_t)r * (DPB * 2) + off16);
    const uint4 b = *(const uint4*)(sbase + (size_t)c * (DPB * 2) + off16);
    float s = 0.f;
    s = absdot(a.x, b.x, wv.x, s);
    s = absdot(a.y, b.y, wv.y, s);
    s = absdot(a.z, b.z, wv.z, s);
    s = absdot(a.w, b.w, wv.w, s);
    return s;
}

// ================= fused cooperative kernel =================
__global__ __launch_bounds__(COOP_BLOCK, 4) void fused_all(
    const float* __restrict__ nodes,
    const int*   __restrict__ r_idx,
    const int*   __restrict__ c_idx,
    const float* __restrict__ w,
    const float* __restrict__ b,
    __half*      __restrict__ tbl2,
    __half*      __restrict__ wh,
    float*       __restrict__ partial,   // [DBLK][E]
    float*       __restrict__ out,
    int n_edges, int n_nodes)
{
    cg::grid_group grid = cg::this_grid();
    const int gid     = blockIdx.x * COOP_BLOCK + threadIdx.x;
    const int gstride = COOP_GRID * COOP_BLOCK;   // 262144

    // ---- phase 1: convert + transpose (+ w) ----
    if (blockIdx.x == 0 && threadIdx.x < (D_FEAT / 8))
        conv_w(w, wh);
    {
        const int total = n_nodes * DBLK;
        for (int t = gid; t < total; t += gstride)
            conv_item(t, nodes, tbl2, n_nodes);
    }

    grid.sync();

    // ---- phase 2: XCD-pinned pair-lane gather ----
    {
        const int kb     = blockIdx.x & (DBLK - 1);     // XCD pin
        const int bchunk = blockIdx.x >> 3;             // 0..127
        const int nblk   = COOP_GRID >> 3;              // 128
        const int pair   = threadIdx.x >> 1;            // 0..127
        const int h      = threadIdx.x & 1;
        const int off16  = h * 16;
        const int estep  = nblk * (COOP_BLOCK / 2);     // 16384 edges/sweep

        const char* sbase = (const char*)(tbl2 + (size_t)kb * n_nodes * DPB);
        const uint4 wv = *(const uint4*)(wh + kb * DPB + h * 8);
        float* pslice = partial + (size_t)kb * n_edges;

        for (int e0 = bchunk * (COOP_BLOCK / 2) + pair; e0 < n_edges;
             e0 += 2 * estep) {
            const int  e1 = e0 + estep;
            const bool v1 = e1 < n_edges;

            const int rA = __builtin_nontemporal_load(r_idx + e0);
            const int cA = __builtin_nontemporal_load(c_idx + e0);
            const int rB = v1 ? __builtin_nontemporal_load(r_idx + e1) : 0;
            const int cB = v1 ? __builtin_nontemporal_load(c_idx + e1) : 0;

            float sA = pair_sum(sbase, wv, rA, cA, off16);
            float sB = pair_sum(sbase, wv, rB, cB, off16);

            sA += __shfl_xor(sA, 1, 64);
            sB += __shfl_xor(sB, 1, 64);

            if (h == 0) {
                __builtin_nontemporal_store(sA, pslice + e0);
                if (v1) __builtin_nontemporal_store(sB, pslice + e1);
            }
        }
    }

    grid.sync();

    // ---- phase 3: out[e] = b + sum_k partial[k][e] ----
    {
        const float bb = b[0];
        const int quads = (n_edges + 3) >> 2;
        for (int q = gid; q < quads; q += gstride) {
            const int e0 = q * 4;
            if (e0 + 4 <= n_edges) {
                float4 acc = make_float4(bb, bb, bb, bb);
                #pragma unroll
                for (int k = 0; k < DBLK; ++k) {
                    const float4 p =
                        *(const float4*)(partial + (size_t)k * n_edges + e0);
                    acc.x += p.x; acc.y += p.y; acc.z += p.z; acc.w += p.w;
                }
                *(float4*)(out + e0) = acc;
            } else {
                for (int e = e0; e < n_edges; ++e) {
                    float acc = bb;
                    for (int k = 0; k < DBLK; ++k)
                        acc += partial[(size_t)k * n_edges + e];
                    out[e] = acc;
                }
            }
        }
    }
}

// ================= non-cooperative fallback path =================
__global__ __launch_bounds__(256) void k_convert(
    const float* __restrict__ src, __half* __restrict__ tbl2,
    const float* __restrict__ w, __half* __restrict__ wh, int n_nodes)
{
    if (blockIdx.x == 0 && threadIdx.x < (D_FEAT / 8))
        conv_w(w, wh);
    const int t = blockIdx.x * blockDim.x + threadIdx.x;
    if (t < n_nodes * DBLK)
        conv_item(t, src, tbl2, n_nodes);
}

__global__ __launch_bounds__(256) void k_gather_pair(
    const __half* __restrict__ tbl2, const __half* __restrict__ wh,
    const int* __restrict__ r_idx, const int* __restrict__ c_idx,
    float* __restrict__ partial, int n_edges, int n_nodes)
{
    const int kb     = blockIdx.x & (DBLK - 1);
    const int bchunk = blockIdx.x >> 3;
    const int pair   = threadIdx.x >> 1;
    const int h      = threadIdx.x & 1;
    const int e      = bchunk * 128 + pair;
    if (e >= n_edges) return;

    const char* sbase = (const char*)(tbl2 + (size_t)kb * n_nodes * DPB);
    const uint4 wv = *(const uint4*)(wh + kb * DPB + h * 8);

    const int r = __builtin_nontemporal_load(r_idx + e);
    const int c = __builtin_nontemporal_load(c_idx + e);
    float s = pair_sum(sbase, wv, r, c, h * 16);
    s += __shfl_xor(s, 1, 64);
    if (h == 0)
        __builtin_nontemporal_store(s, partial + (size_t)kb * n_edges + e);
}

__global__ __launch_bounds__(256) void k_reduce(
    const float* __restrict__ partial, const float* __restrict__ b,
    float* __restrict__ out, int n_edges)
{
    const int q  = blockIdx.x * blockDim.x + threadIdx.x;
    const int e0 = q * 4;
    if (e0 >= n_edges) return;
    const float bb = b[0];
    if (e0 + 4 <= n_edges) {
        float4 acc = make_float4(bb, bb, bb, bb);
        #pragma unroll
        for (int k = 0; k < DBLK; ++k) {
            const float4 p = *(const float4*)(partial + (size_t)k * n_edges + e0);
            acc.x += p.x; acc.y += p.y; acc.z += p.z; acc.w += p.w;
        }
        *(float4*)(out + e0) = acc;
    } else {
        for (int e = e0; e < n_edges; ++e) {
            float acc = bb;
            for (int k = 0; k < DBLK; ++k)
                acc += partial[(size_t)k * n_edges + e];
            out[e] = acc;
        }
    }
}

// ---- last-resort: direct fp32 gather if ws too small ----
__global__ __launch_bounds__(256) void gather_edges_f32(
    const float* __restrict__ nodes,
    const int*   __restrict__ r_idx,
    const int*   __restrict__ c_idx,
    const float* __restrict__ w,
    const float* __restrict__ b,
    float*       __restrict__ out,
    int n_edges)
{
    const int tid  = blockIdx.x * blockDim.x + threadIdx.x;
    const int lane = tid & 31;
    const int edge = tid >> 5;
    if (edge >= n_edges) return;

    const int r = r_idx[edge];
    const int c = c_idx[edge];

    const float4 wv = ((const float4*)w)[lane];
    const float4 av = ((const float4*)(nodes + (size_t)r * D_FEAT))[lane];
    const float4 bv = ((const float4*)(nodes + (size_t)c * D_FEAT))[lane];

    float s = fabsf(av.x - bv.x) * wv.x
            + fabsf(av.y - bv.y) * wv.y
            + fabsf(av.z - bv.z) * wv.z
            + fabsf(av.w - bv.w) * wv.w;

    #pragma unroll
    for (int off = 16; off > 0; off >>= 1)
        s += __shfl_xor(s, off, 64);

    if (lane == 0)
        out[edge] = s + b[0];
}

extern "C" void kernel_launch(void* const* d_in, const int* in_sizes, int n_in,
                              void* d_out, int out_size, void* d_ws, size_t ws_size,
                              hipStream_t stream) {
    const float* nodes = (const float*)d_in[0];   // [N_NODES, 128] f32
    const int*   r_idx = (const int*)d_in[1];     // [E] int32
    const int*   c_idx = (const int*)d_in[2];     // [E] int32
    const float* w     = (const float*)d_in[3];   // [128, 1] f32
    const float* b     = (const float*)d_in[4];   // [1] f32
    float*       out   = (float*)d_out;           // [E] f32

    const int n_edges   = in_sizes[1];
    const int n_nodes_f = in_sizes[0];            // n_nodes * 128 floats
    const int n_nodes   = n_nodes_f / D_FEAT;

    const size_t tbl_bytes  = (size_t)n_nodes_f * sizeof(__half);     // 25.6 MB
    const size_t wh_bytes   = 256;                                    // padded
    const size_t part_bytes = (size_t)DBLK * n_edges * sizeof(float); // 19.2 MB

    static int coop_ok = -1;
    if (coop_ok < 0) {
        hipDeviceProp_t prop;
        coop_ok = (hipGetDeviceProperties(&prop, 0) == hipSuccess &&
                   prop.cooperativeLaunch) ? 1 : 0;
    }

    if (ws_size >= tbl_bytes + wh_bytes + part_bytes &&
        (n_nodes_f % D_FEAT) == 0) {
        __half* tbl2    = (__half*)d_ws;
        __half* wh      = (__half*)((char*)d_ws + tbl_bytes);
        float*  partial = (float*)((char*)d_ws + tbl_bytes + wh_bytes);

        if (coop_ok) {
            void* args[] = {
                (void*)&nodes, (void*)&r_idx, (void*)&c_idx, (void*)&w,
                (void*)&b, (void*)&tbl2, (void*)&wh, (void*)&partial,
                (void*)&out, (void*)&n_edges, (void*)&n_nodes
            };
            hipLaunchCooperativeKernel((const void*)fused_all,
                                       dim3(COOP_GRID), dim3(COOP_BLOCK),
                                       args, 0, stream);
        } else {
            {
                const int total = n_nodes * DBLK;
                const int grid  = (total + 255) / 256;
                k_convert<<<grid, 256, 0, stream>>>(nodes, tbl2, w, wh, n_nodes);
            }
            {
                const int chunks = (n_edges + 127) / 128;
                k_gather_pair<<<chunks * DBLK, 256, 0, stream>>>(
                    tbl2, wh, r_idx, c_idx, partial, n_edges, n_nodes);
            }
            {
                const int quads = (n_edges + 3) / 4;
                const int grid  = (quads + 255) / 256;
                k_reduce<<<grid, 256, 0, stream>>>(partial, b, out, n_edges);
            }
        }
    } else {
        const int block = 256;
        const int grid  = (int)(((long long)n_edges * 32 + block - 1) / block);
        gather_edges_f32<<<grid, block, 0, stream>>>(
            nodes, r_idx, c_idx, w, b, out, n_edges);
    }
}

// Round 5
// 168.188 us; speedup vs baseline: 2.7011x; 2.7011x over previous
//
#include <hip/hip_runtime.h>
#include <hip/hip_bf16.h>
#include <hip/hip_fp16.h>
#include <stdint.h>

// out[e] = sum_d |nodes[r[e]][d] - nodes[c[e]][d]| * w[d] + b[0]
// E = 600000, D = 128, N_OUT = 1.
//
// R1: fp32 gather, 85 us (miss-path bound, FETCH 287 MB).
// R2: fp16 table, 42 us gather (FETCH 132 MB, ~3.1 TB/s miss path).
// R3/R4: ILP + packed fdot2: neutral -> not VALU, not MLP.
// R5: dim-partitioned XCD-pinned slices (tbl2[k][node][16] fp16, 3.2 MB
//     per slice, blockIdx%8 = XCD): FETCH 31 MB => slices L2-resident.
//     But gather 58 us: rp[0]/rp[1] are 2 instrs to the SAME 64B line =>
//     19.2M line-requests @ ~0.5 lines/cy/CU == 58 us. Request-rate bound.
// R6: cooperative fusion of all 3 passes: 371 us, ALL pipes idle ->
//     grid.sync()/co-residency serialization. REVERTED.
// R7 (this): R5 3-kernel structure + pair-lane gather: 2 lanes per
//     (edge, dblk), lane h reads the h-th 16B half of the node's 32B chunk
//     -> same-line lanes merge into ONE line request per endpoint
//     (9.6M total, half of R5). 4-edge unrolled loop per thread -> 16
//     independent gathers in flight. Predict gather ~28-32 us.

#define D_FEAT 128
#define DBLK   8      // dim blocks (== XCD count)
#define DPB    16     // halves per node per slice (32 B)
#define GITER  4      // edges per thread in gather

typedef _Float16 h2v __attribute__((ext_vector_type(2)));

// ---- packed abs-diff dot: acc += dot(|a-b|, w) over 2 halves ----
__device__ __forceinline__ float absdot(uint32_t a, uint32_t b, uint32_t w,
                                        float acc)
{
#if __has_builtin(__builtin_amdgcn_fdot2)
    const h2v av = __builtin_bit_cast(h2v, a);
    const h2v bv = __builtin_bit_cast(h2v, b);
    const h2v d  = av - bv;                                   // v_pk_sub_f16
    const uint32_t ad = __builtin_bit_cast(uint32_t, d) & 0x7FFF7FFFu;
    return __builtin_amdgcn_fdot2(__builtin_bit_cast(h2v, ad),
                                  __builtin_bit_cast(h2v, w), acc, false);
#else
    const float2 x = __half22float2(__builtin_bit_cast(__half2, a));
    const float2 y = __half22float2(__builtin_bit_cast(__half2, b));
    const float2 ww = __half22float2(__builtin_bit_cast(__half2, w));
    return acc + fabsf(x.x - y.x) * ww.x + fabsf(x.y - y.y) * ww.y;
#endif
}

// ---- pass 1: fp32 -> fp16 convert + transpose to [k][node][16] ----
__global__ __launch_bounds__(256) void k_convert(
    const float* __restrict__ src, __half* __restrict__ tbl2,
    const float* __restrict__ w, __half* __restrict__ wh, int n_nodes)
{
    // 16 threads of block 0 convert w (128 f32 -> 128 f16, linear order)
    if (blockIdx.x == 0 && threadIdx.x < (D_FEAT / 8)) {
        const float4* s = (const float4*)w + 2 * (size_t)threadIdx.x;
        const float4 a = s[0];
        const float4 c = s[1];
        float4 packed;
        ((__half2*)&packed)[0] = __floats2half2_rn(a.x, a.y);
        ((__half2*)&packed)[1] = __floats2half2_rn(a.z, a.w);
        ((__half2*)&packed)[2] = __floats2half2_rn(c.x, c.y);
        ((__half2*)&packed)[3] = __floats2half2_rn(c.z, c.w);
        ((float4*)wh)[threadIdx.x] = packed;
    }

    const int t = blockIdx.x * blockDim.x + threadIdx.x;
    const int n = t >> 3;
    const int k = t & (DBLK - 1);
    if (n >= n_nodes) return;

    const float4* s = (const float4*)(src + (size_t)n * D_FEAT + k * DPB);
    const float4 f0 = s[0], f1 = s[1], f2 = s[2], f3 = s[3];
    uint4 p0, p1;
    __half2* h0 = (__half2*)&p0;
    __half2* h1 = (__half2*)&p1;
    h0[0] = __floats2half2_rn(f0.x, f0.y);
    h0[1] = __floats2half2_rn(f0.z, f0.w);
    h0[2] = __floats2half2_rn(f1.x, f1.y);
    h0[3] = __floats2half2_rn(f1.z, f1.w);
    h1[0] = __floats2half2_rn(f2.x, f2.y);
    h1[1] = __floats2half2_rn(f2.z, f2.w);
    h1[2] = __floats2half2_rn(f3.x, f3.y);
    h1[3] = __floats2half2_rn(f3.z, f3.w);

    uint4* d = (uint4*)(tbl2 + ((size_t)k * n_nodes + n) * DPB);
    d[0] = p0;
    d[1] = p1;
}

// ---- one (edge, kb, h) pair-lane item -> 8-dim partial sum ----
__device__ __forceinline__ float pair_sum(const char* __restrict__ sbase,
                                          const uint4 wv, int r, int c,
                                          int off16)
{
    const uint4 a = *(const uint4*)(sbase + (size_t)r * (DPB * 2) + off16);
    const uint4 b = *(const uint4*)(sbase + (size_t)c * (DPB * 2) + off16);
    float s = 0.f;
    s = absdot(a.x, b.x, wv.x, s);
    s = absdot(a.y, b.y, wv.y, s);
    s = absdot(a.z, b.z, wv.z, s);
    s = absdot(a.w, b.w, wv.w, s);
    return s;
}

// ---- pass 2: XCD-pinned pair-lane gather, GITER edges/thread ----
// blockIdx%8 = dim block = XCD (round-robin dispatch). 2 lanes per edge:
// lanes 2p/2p+1 read the two 16B halves of each endpoint's 32B chunk ->
// hardware merges them into one 64B line request per endpoint.
__global__ __launch_bounds__(256) void k_gather_pair(
    const __half* __restrict__ tbl2, const __half* __restrict__ wh,
    const int* __restrict__ r_idx, const int* __restrict__ c_idx,
    float* __restrict__ partial, int n_edges, int n_nodes)
{
    const int kb     = blockIdx.x & (DBLK - 1);
    const int bchunk = blockIdx.x >> 3;
    const int pair   = threadIdx.x >> 1;     // 0..127
    const int h      = threadIdx.x & 1;
    const int off16  = h * 16;

    const char* sbase = (const char*)(tbl2 + (size_t)kb * n_nodes * DPB);
    const uint4 wv = *(const uint4*)(wh + kb * DPB + h * 8);
    float* pslice = partial + (size_t)kb * n_edges;

    const int base_e = bchunk * (128 * GITER) + pair;

    int  e[GITER], r[GITER], c[GITER];
    bool v[GITER];
    #pragma unroll
    for (int i = 0; i < GITER; ++i) {
        e[i] = base_e + i * 128;
        v[i] = e[i] < n_edges;
        // nt: 4.8 MB/XCD of index stream must not evict the pinned slice
        r[i] = v[i] ? __builtin_nontemporal_load(r_idx + e[i]) : 0;
        c[i] = v[i] ? __builtin_nontemporal_load(c_idx + e[i]) : 0;
    }

    float s[GITER];
    #pragma unroll
    for (int i = 0; i < GITER; ++i)
        s[i] = pair_sum(sbase, wv, r[i], c[i], off16);

    #pragma unroll
    for (int i = 0; i < GITER; ++i) {
        s[i] += __shfl_xor(s[i], 1, 64);
        if (h == 0 && v[i])
            __builtin_nontemporal_store(s[i], pslice + e[i]);
    }
}

// ---- pass 3: out[e] = b + sum_k partial[k][e], 4 edges/thread ----
__global__ __launch_bounds__(256) void k_reduce(
    const float* __restrict__ partial, const float* __restrict__ b,
    float* __restrict__ out, int n_edges)
{
    const int q  = blockIdx.x * blockDim.x + threadIdx.x;
    const int e0 = q * 4;
    if (e0 >= n_edges) return;
    const float bb = b[0];
    if (e0 + 4 <= n_edges) {
        float4 acc = make_float4(bb, bb, bb, bb);
        #pragma unroll
        for (int k = 0; k < DBLK; ++k) {
            const float4 p =
                *(const float4*)(partial + (size_t)k * n_edges + e0);
            acc.x += p.x; acc.y += p.y; acc.z += p.z; acc.w += p.w;
        }
        *(float4*)(out + e0) = acc;
    } else {
        for (int e = e0; e < n_edges; ++e) {
            float acc = bb;
            for (int k = 0; k < DBLK; ++k)
                acc += partial[(size_t)k * n_edges + e];
            out[e] = acc;
        }
    }
}

// ---- last-resort: direct fp32 gather if ws too small ----
__global__ __launch_bounds__(256) void gather_edges_f32(
    const float* __restrict__ nodes,
    const int*   __restrict__ r_idx,
    const int*   __restrict__ c_idx,
    const float* __restrict__ w,
    const float* __restrict__ b,
    float*       __restrict__ out,
    int n_edges)
{
    const int tid  = blockIdx.x * blockDim.x + threadIdx.x;
    const int lane = tid & 31;
    const int edge = tid >> 5;
    if (edge >= n_edges) return;

    const int r = r_idx[edge];
    const int c = c_idx[edge];

    const float4 wv = ((const float4*)w)[lane];
    const float4 av = ((const float4*)(nodes + (size_t)r * D_FEAT))[lane];
    const float4 bv = ((const float4*)(nodes + (size_t)c * D_FEAT))[lane];

    float s = fabsf(av.x - bv.x) * wv.x
            + fabsf(av.y - bv.y) * wv.y
            + fabsf(av.z - bv.z) * wv.z
            + fabsf(av.w - bv.w) * wv.w;

    #pragma unroll
    for (int off = 16; off > 0; off >>= 1)
        s += __shfl_xor(s, off, 64);

    if (lane == 0)
        out[edge] = s + b[0];
}

extern "C" void kernel_launch(void* const* d_in, const int* in_sizes, int n_in,
                              void* d_out, int out_size, void* d_ws, size_t ws_size,
                              hipStream_t stream) {
    const float* nodes = (const float*)d_in[0];   // [N_NODES, 128] f32
    const int*   r_idx = (const int*)d_in[1];     // [E] int32
    const int*   c_idx = (const int*)d_in[2];     // [E] int32
    const float* w     = (const float*)d_in[3];   // [128, 1] f32
    const float* b     = (const float*)d_in[4];   // [1] f32
    float*       out   = (float*)d_out;           // [E] f32

    const int n_edges   = in_sizes[1];
    const int n_nodes_f = in_sizes[0];            // n_nodes * 128 floats
    const int n_nodes   = n_nodes_f / D_FEAT;

    const size_t tbl_bytes  = (size_t)n_nodes_f * sizeof(__half);     // 25.6 MB
    const size_t wh_bytes   = 256;                                    // padded
    const size_t part_bytes = (size_t)DBLK * n_edges * sizeof(float); // 19.2 MB

    if (ws_size >= tbl_bytes + wh_bytes + part_bytes &&
        (n_nodes_f % D_FEAT) == 0) {
        __half* tbl2    = (__half*)d_ws;
        __half* wh      = (__half*)((char*)d_ws + tbl_bytes);
        float*  partial = (float*)((char*)d_ws + tbl_bytes + wh_bytes);

        // pass 1: convert + transpose
        {
            const int total = n_nodes * DBLK;
            const int grid  = (total + 255) / 256;
            k_convert<<<grid, 256, 0, stream>>>(nodes, tbl2, w, wh, n_nodes);
        }
        // pass 2: XCD-pinned pair-lane gather
        {
            const int epb    = 128 * GITER;             // edges per block
            const int chunks = (n_edges + epb - 1) / epb;
            k_gather_pair<<<chunks * DBLK, 256, 0, stream>>>(
                tbl2, wh, r_idx, c_idx, partial, n_edges, n_nodes);
        }
        // pass 3: reduce partials
        {
            const int quads = (n_edges + 3) / 4;
            const int grid  = (quads + 255) / 256;
            k_reduce<<<grid, 256, 0, stream>>>(partial, b, out, n_edges);
        }
    } else {
        const int block = 256;
        const int grid  = (int)(((long long)n_edges * 32 + block - 1) / block);
        gather_edges_f32<<<grid, block, 0, stream>>>(
            nodes, r_idx, c_idx, w, b, out, n_edges);
    }
}

// Round 6
// 153.745 us; speedup vs baseline: 2.9549x; 1.0939x over previous
//
#include <hip/hip_runtime.h>
#include <hip/hip_bf16.h>
#include <hip/hip_fp16.h>
#include <stdint.h>

// out[e] = sum_d |nodes[r[e]][d] - nodes[c[e]][d]| * w[d] + b[0]
// E = 600000, D = 128, N_OUT = 1.
//
// R1: fp32 gather, 85 us (miss-path bound, FETCH 287 MB).
// R2: fp16 table, 42 us gather (FETCH 132 MB, ~3.1 TB/s miss path).
// R3/R4: ILP + packed fdot2: neutral -> not VALU, not MLP.
// R5: dim-partitioned XCD-pinned slices (tbl2[k][node][16] fp16, 3.2 MB
//     per slice, blockIdx%8 = XCD): FETCH 31 MB => L2-resident. Gather
//     58 us: bound by per-LANE request rate (~0.55 req/cy/CU).
// R6: cooperative fusion: 371 us, grid.sync serialization. REVERTED.
// R7: pair-lane gather: 69 us. Same-line lanes do NOT merge; duplicated
//     index loads ADDED requests. Lane-request accounting fits R5/R7.
// R8 (this): R5 structure + request-count cuts:
//   a) indices pre-packed to uint64 (r | c<<32) in convert pass ->
//      1x8B idx load per (edge,dblk) instead of 2x4B (idx reqs halved).
//   b) GITER=2 edges/thread -> 8 independent gathers in flight.
//   Gather loads stay PLAIN (nt would mark slice lines evict-first in L2
//   and break residency). Predict gather ~50 us, total ~145.

#define D_FEAT 128
#define DBLK   8      // dim blocks (== XCD count)
#define DPB    16     // halves per node per slice (32 B)
#define GEDGES 512    // edges per gather block (2 per thread)

typedef _Float16 h2v __attribute__((ext_vector_type(2)));

// ---- packed abs-diff dot: acc += dot(|a-b|, w) over 2 halves ----
__device__ __forceinline__ float absdot(uint32_t a, uint32_t b, uint32_t w,
                                        float acc)
{
#if __has_builtin(__builtin_amdgcn_fdot2)
    const h2v av = __builtin_bit_cast(h2v, a);
    const h2v bv = __builtin_bit_cast(h2v, b);
    const h2v d  = av - bv;                                   // v_pk_sub_f16
    const uint32_t ad = __builtin_bit_cast(uint32_t, d) & 0x7FFF7FFFu;
    return __builtin_amdgcn_fdot2(__builtin_bit_cast(h2v, ad),
                                  __builtin_bit_cast(h2v, w), acc, false);
#else
    const float2 x = __half22float2(__builtin_bit_cast(__half2, a));
    const float2 y = __half22float2(__builtin_bit_cast(__half2, b));
    const float2 ww = __half22float2(__builtin_bit_cast(__half2, w));
    return acc + fabsf(x.x - y.x) * ww.x + fabsf(x.y - y.y) * ww.y;
#endif
}

// ---- pass 1: fp32 -> fp16 convert + transpose + (r,c) pack ----
__global__ __launch_bounds__(256) void k_convert(
    const float* __restrict__ src, __half* __restrict__ tbl2,
    const float* __restrict__ w, __half* __restrict__ wh,
    const int* __restrict__ r_idx, const int* __restrict__ c_idx,
    uint64_t* __restrict__ rc,
    int n_nodes, int n_edges)
{
    // 16 threads of block 0 convert w (128 f32 -> 128 f16, linear order)
    if (blockIdx.x == 0 && threadIdx.x < (D_FEAT / 8)) {
        const float4* s = (const float4*)w + 2 * (size_t)threadIdx.x;
        const float4 a = s[0];
        const float4 c = s[1];
        float4 packed;
        ((__half2*)&packed)[0] = __floats2half2_rn(a.x, a.y);
        ((__half2*)&packed)[1] = __floats2half2_rn(a.z, a.w);
        ((__half2*)&packed)[2] = __floats2half2_rn(c.x, c.y);
        ((__half2*)&packed)[3] = __floats2half2_rn(c.z, c.w);
        ((float4*)wh)[threadIdx.x] = packed;
    }

    const int t = blockIdx.x * blockDim.x + threadIdx.x;

    // (r,c) packing: one uint64 per edge
    if (t < n_edges) {
        const uint64_t rr = (uint32_t)r_idx[t];
        const uint64_t cc = (uint32_t)c_idx[t];
        rc[t] = rr | (cc << 32);
    }

    // table transpose: item t -> node t>>3, dim-block t&7
    const int n = t >> 3;
    const int k = t & (DBLK - 1);
    if (n >= n_nodes) return;

    const float4* s = (const float4*)(src + (size_t)n * D_FEAT + k * DPB);
    const float4 f0 = s[0], f1 = s[1], f2 = s[2], f3 = s[3];
    uint4 p0, p1;
    __half2* h0 = (__half2*)&p0;
    __half2* h1 = (__half2*)&p1;
    h0[0] = __floats2half2_rn(f0.x, f0.y);
    h0[1] = __floats2half2_rn(f0.z, f0.w);
    h0[2] = __floats2half2_rn(f1.x, f1.y);
    h0[3] = __floats2half2_rn(f1.z, f1.w);
    h1[0] = __floats2half2_rn(f2.x, f2.y);
    h1[1] = __floats2half2_rn(f2.z, f2.w);
    h1[2] = __floats2half2_rn(f3.x, f3.y);
    h1[3] = __floats2half2_rn(f3.z, f3.w);

    uint4* d = (uint4*)(tbl2 + ((size_t)k * n_nodes + n) * DPB);
    d[0] = p0;
    d[1] = p1;
}

// ---- one (edge, kb) item: 4x16B gathers -> 16-dim partial sum ----
__device__ __forceinline__ float edge_sum(const char* __restrict__ sbase,
                                          const uint4 w0, const uint4 w1,
                                          uint64_t q)
{
    const char* rp = sbase + (size_t)(uint32_t)q * (DPB * 2);
    const char* cp = sbase + (size_t)(uint32_t)(q >> 32) * (DPB * 2);
    const uint4 a0 = *(const uint4*)rp;
    const uint4 a1 = *(const uint4*)(rp + 16);
    const uint4 b0 = *(const uint4*)cp;
    const uint4 b1 = *(const uint4*)(cp + 16);
    float s0 = 0.f, s1 = 0.f;
    s0 = absdot(a0.x, b0.x, w0.x, s0);
    s0 = absdot(a0.y, b0.y, w0.y, s0);
    s0 = absdot(a0.z, b0.z, w0.z, s0);
    s0 = absdot(a0.w, b0.w, w0.w, s0);
    s1 = absdot(a1.x, b1.x, w1.x, s1);
    s1 = absdot(a1.y, b1.y, w1.y, s1);
    s1 = absdot(a1.z, b1.z, w1.z, s1);
    s1 = absdot(a1.w, b1.w, w1.w, s1);
    return s0 + s1;
}

// ---- pass 2: XCD-pinned gather, 2 edges/thread ----
// blockIdx%8 = dim block = XCD (round-robin dispatch). One thread per
// (edge, dblk): 4 independent 16B loads within the XCD-local 3.2 MB slice.
__global__ __launch_bounds__(256) void k_gather(
    const __half* __restrict__ tbl2, const __half* __restrict__ wh,
    const uint64_t* __restrict__ rc,
    float* __restrict__ partial, int n_edges, int n_nodes)
{
    const int kb     = blockIdx.x & (DBLK - 1);
    const int bchunk = blockIdx.x >> 3;
    const int eA     = bchunk * GEDGES + threadIdx.x;
    const int eB     = eA + 256;

    const char* sbase = (const char*)(tbl2 + (size_t)kb * n_nodes * DPB);
    const uint4* wp = (const uint4*)(wh + kb * DPB);
    const uint4 w0 = wp[0], w1 = wp[1];
    float* pslice = partial + (size_t)kb * n_edges;

    const bool vA = eA < n_edges;
    const bool vB = eB < n_edges;

    // nt: 4.8 MB/XCD of index stream must not evict the pinned slice
    const uint64_t qA = vA ? __builtin_nontemporal_load(rc + eA) : 0;
    const uint64_t qB = vB ? __builtin_nontemporal_load(rc + eB) : 0;

    const float sA = edge_sum(sbase, w0, w1, qA);
    const float sB = edge_sum(sbase, w0, w1, qB);

    if (vA) __builtin_nontemporal_store(sA, pslice + eA);
    if (vB) __builtin_nontemporal_store(sB, pslice + eB);
}

// ---- pass 3: out[e] = b + sum_k partial[k][e], 4 edges/thread ----
__global__ __launch_bounds__(256) void k_reduce(
    const float* __restrict__ partial, const float* __restrict__ b,
    float* __restrict__ out, int n_edges)
{
    const int q  = blockIdx.x * blockDim.x + threadIdx.x;
    const int e0 = q * 4;
    if (e0 >= n_edges) return;
    const float bb = b[0];
    if (e0 + 4 <= n_edges) {
        float4 acc = make_float4(bb, bb, bb, bb);
        #pragma unroll
        for (int k = 0; k < DBLK; ++k) {
            const float4 p =
                *(const float4*)(partial + (size_t)k * n_edges + e0);
            acc.x += p.x; acc.y += p.y; acc.z += p.z; acc.w += p.w;
        }
        *(float4*)(out + e0) = acc;
    } else {
        for (int e = e0; e < n_edges; ++e) {
            float acc = bb;
            for (int k = 0; k < DBLK; ++k)
                acc += partial[(size_t)k * n_edges + e];
            out[e] = acc;
        }
    }
}

// ---- last-resort: direct fp32 gather if ws too small ----
__global__ __launch_bounds__(256) void gather_edges_f32(
    const float* __restrict__ nodes,
    const int*   __restrict__ r_idx,
    const int*   __restrict__ c_idx,
    const float* __restrict__ w,
    const float* __restrict__ b,
    float*       __restrict__ out,
    int n_edges)
{
    const int tid  = blockIdx.x * blockDim.x + threadIdx.x;
    const int lane = tid & 31;
    const int edge = tid >> 5;
    if (edge >= n_edges) return;

    const int r = r_idx[edge];
    const int c = c_idx[edge];

    const float4 wv = ((const float4*)w)[lane];
    const float4 av = ((const float4*)(nodes + (size_t)r * D_FEAT))[lane];
    const float4 bv = ((const float4*)(nodes + (size_t)c * D_FEAT))[lane];

    float s = fabsf(av.x - bv.x) * wv.x
            + fabsf(av.y - bv.y) * wv.y
            + fabsf(av.z - bv.z) * wv.z
            + fabsf(av.w - bv.w) * wv.w;

    #pragma unroll
    for (int off = 16; off > 0; off >>= 1)
        s += __shfl_xor(s, off, 64);

    if (lane == 0)
        out[edge] = s + b[0];
}

extern "C" void kernel_launch(void* const* d_in, const int* in_sizes, int n_in,
                              void* d_out, int out_size, void* d_ws, size_t ws_size,
                              hipStream_t stream) {
    const float* nodes = (const float*)d_in[0];   // [N_NODES, 128] f32
    const int*   r_idx = (const int*)d_in[1];     // [E] int32
    const int*   c_idx = (const int*)d_in[2];     // [E] int32
    const float* w     = (const float*)d_in[3];   // [128, 1] f32
    const float* b     = (const float*)d_in[4];   // [1] f32
    float*       out   = (float*)d_out;           // [E] f32

    const int n_edges   = in_sizes[1];
    const int n_nodes_f = in_sizes[0];            // n_nodes * 128 floats
    const int n_nodes   = n_nodes_f / D_FEAT;

    const size_t tbl_bytes  = (size_t)n_nodes_f * sizeof(__half);     // 25.6 MB
    const size_t wh_bytes   = 256;                                    // padded
    const size_t rc_bytes   = (size_t)n_edges * sizeof(uint64_t);     // 4.8 MB
    const size_t part_bytes = (size_t)DBLK * n_edges * sizeof(float); // 19.2 MB

    if (ws_size >= tbl_bytes + wh_bytes + rc_bytes + part_bytes &&
        (n_nodes_f % D_FEAT) == 0) {
        __half*   tbl2    = (__half*)d_ws;
        __half*   wh      = (__half*)((char*)d_ws + tbl_bytes);
        uint64_t* rc      = (uint64_t*)((char*)d_ws + tbl_bytes + wh_bytes);
        float*    partial = (float*)((char*)d_ws + tbl_bytes + wh_bytes
                                     + rc_bytes);

        // pass 1: convert + transpose + index pack
        {
            const int total = n_nodes * DBLK;
            const int items = total > n_edges ? total : n_edges;
            const int grid  = (items + 255) / 256;
            k_convert<<<grid, 256, 0, stream>>>(
                nodes, tbl2, w, wh, r_idx, c_idx, rc, n_nodes, n_edges);
        }
        // pass 2: XCD-pinned gather (2 edges/thread)
        {
            const int chunks = (n_edges + GEDGES - 1) / GEDGES;
            k_gather<<<chunks * DBLK, 256, 0, stream>>>(
                tbl2, wh, rc, partial, n_edges, n_nodes);
        }
        // pass 3: reduce partials
        {
            const int quads = (n_edges + 3) / 4;
            const int grid  = (quads + 255) / 256;
            k_reduce<<<grid, 256, 0, stream>>>(partial, b, out, n_edges);
        }
    } else {
        const int block = 256;
        const int grid  = (int)(((long long)n_edges * 32 + block - 1) / block);
        gather_edges_f32<<<grid, block, 0, stream>>>(
            nodes, r_idx, c_idx, w, b, out, n_edges);
    }
}

// Round 7
// 152.816 us; speedup vs baseline: 2.9728x; 1.0061x over previous
//
#include <hip/hip_runtime.h>
#include <hip/hip_bf16.h>
#include <hip/hip_fp16.h>
#include <stdint.h>

// out[e] = sum_d |nodes[r[e]][d] - nodes[c[e]][d]| * w[d] + b[0]
// E = 600000, D = 128, N_OUT = 1.
//
// R1: fp32 single-kernel gather: 85 us, total 129 (FETCH 287 MB, HBM-satur.)
// R2: fp16 table: gather 42 us but convert pays ~40 (drain of 268 MB poison
//     dirt lands on first kernel) -> total 130. FETCH 132 MB vs 25.6 MB
//     table => ~5x L3 re-fetch (per-XCD L3 retention).
// R3/R4: ILP + packed fdot2: neutral. R7/R8: request-count cuts: neutral.
//     => only GATHERED BYTES and LOCALITY ever moved the needle.
// R5: dim-partitioned 32B chunks, XCD-pinned: FETCH 31 MB (locality works!)
//     but 64 random lines/instr (vs R2's 16 fully-used) -> 58 us. Coalescing
//     loss ate the locality gain.
// R6: cooperative fusion: 371 us (grid.sync serialization). REVERTED.
// R9 (this): stripe partition of the ORIGINAL fp32 rows: 4 stripes x 32
//     dims (128 B). Stripe k pinned to XCDs {k,k+4} via blockIdx&3 ->
//     12.8 MB footprint/XCD (L3-share resident). 8 lanes/edge read 128 B
//     contiguous (R2 coalescing: 16 fully-used lines/instr). No convert
//     kernel (stripes are column ranges of the input), fp32-exact, 2
//     kernels. Partials stored PLAIN (L2-resident for reduce).
//     Predict: gather FETCH 60-90 MB, dur 55-65 us (worst 85 if
//     request-rate-capped); total ~107-118.

#define D_FEAT   128
#define NSTRIPE  4      // column stripes; stripe k -> XCDs {k, k+4}
#define DPS      32     // dims per stripe (128 B fp32)
#define SLANES   8      // lanes per edge (8 x float4 = 128 B)
#define EPB      64     // edges per block (2 per 8-lane group)

// ---- pass 1: XCD-pinned stripe gather, fp32 direct from nodes ----
// blockIdx&3 = stripe (blockIdx%8 round-robins XCDs, so stripe k lands on
// XCDs k and k+4 only). Per 8-lane group: one edge; lane l reads float4
// #l of each endpoint's 128 B stripe segment -> per wave-instruction:
// 8 edges x 128 B contiguous = 16 fully-used 64 B lines.
__global__ __launch_bounds__(256) void k_gather_stripe(
    const float* __restrict__ nodes,
    const int*   __restrict__ r_idx,
    const int*   __restrict__ c_idx,
    const float* __restrict__ w,
    float*       __restrict__ partial,   // [NSTRIPE][E]
    int n_edges)
{
    const int kb = blockIdx.x & (NSTRIPE - 1);
    const int bc = blockIdx.x >> 2;
    const int l  = threadIdx.x & (SLANES - 1);
    const int g  = threadIdx.x >> 3;            // 0..31

    const float* sbase = nodes + kb * DPS;      // column offset of stripe
    const float4 wv = *(const float4*)(w + kb * DPS + l * 4);
    float* pslice = partial + (size_t)kb * n_edges;

    const int eA = bc * EPB + g;
    const int eB = eA + 32;
    const bool vA = eA < n_edges;
    const bool vB = eB < n_edges;

    const int rA = vA ? r_idx[eA] : 0;
    const int cA = vA ? c_idx[eA] : 0;
    const int rB = vB ? r_idx[eB] : 0;
    const int cB = vB ? c_idx[eB] : 0;

    // 4 independent 16B gathers in flight
    const float4 aA = *(const float4*)(sbase + (size_t)rA * D_FEAT + l * 4);
    const float4 bA = *(const float4*)(sbase + (size_t)cA * D_FEAT + l * 4);
    const float4 aB = *(const float4*)(sbase + (size_t)rB * D_FEAT + l * 4);
    const float4 bB = *(const float4*)(sbase + (size_t)cB * D_FEAT + l * 4);

    float sA = fabsf(aA.x - bA.x) * wv.x + fabsf(aA.y - bA.y) * wv.y
             + fabsf(aA.z - bA.z) * wv.z + fabsf(aA.w - bA.w) * wv.w;
    float sB = fabsf(aB.x - bB.x) * wv.x + fabsf(aB.y - bB.y) * wv.y
             + fabsf(aB.z - bB.z) * wv.z + fabsf(aB.w - bB.w) * wv.w;

    // reduce across the 8-lane group (xor masks < 8 stay in group)
    #pragma unroll
    for (int off = 4; off > 0; off >>= 1) {
        sA += __shfl_xor(sA, off, 64);
        sB += __shfl_xor(sB, off, 64);
    }

    if (l == 0) {
        if (vA) pslice[eA] = sA;   // plain store: keep L2-resident for reduce
        if (vB) pslice[eB] = sB;
    }
}

// ---- pass 2: out[e] = b + sum_k partial[k][e], 4 edges/thread ----
__global__ __launch_bounds__(256) void k_reduce(
    const float* __restrict__ partial, const float* __restrict__ b,
    float* __restrict__ out, int n_edges)
{
    const int q  = blockIdx.x * blockDim.x + threadIdx.x;
    const int e0 = q * 4;
    if (e0 >= n_edges) return;
    const float bb = b[0];
    if (e0 + 4 <= n_edges) {
        float4 acc = make_float4(bb, bb, bb, bb);
        #pragma unroll
        for (int k = 0; k < NSTRIPE; ++k) {
            const float4 p =
                *(const float4*)(partial + (size_t)k * n_edges + e0);
            acc.x += p.x; acc.y += p.y; acc.z += p.z; acc.w += p.w;
        }
        *(float4*)(out + e0) = acc;
    } else {
        for (int e = e0; e < n_edges; ++e) {
            float acc = bb;
            for (int k = 0; k < NSTRIPE; ++k)
                acc += partial[(size_t)k * n_edges + e];
            out[e] = acc;
        }
    }
}

// ---- last-resort: direct fp32 gather if ws too small ----
__global__ __launch_bounds__(256) void gather_edges_f32(
    const float* __restrict__ nodes,
    const int*   __restrict__ r_idx,
    const int*   __restrict__ c_idx,
    const float* __restrict__ w,
    const float* __restrict__ b,
    float*       __restrict__ out,
    int n_edges)
{
    const int tid  = blockIdx.x * blockDim.x + threadIdx.x;
    const int lane = tid & 31;
    const int edge = tid >> 5;
    if (edge >= n_edges) return;

    const int r = r_idx[edge];
    const int c = c_idx[edge];

    const float4 wv = ((const float4*)w)[lane];
    const float4 av = ((const float4*)(nodes + (size_t)r * D_FEAT))[lane];
    const float4 bv = ((const float4*)(nodes + (size_t)c * D_FEAT))[lane];

    float s = fabsf(av.x - bv.x) * wv.x
            + fabsf(av.y - bv.y) * wv.y
            + fabsf(av.z - bv.z) * wv.z
            + fabsf(av.w - bv.w) * wv.w;

    #pragma unroll
    for (int off = 16; off > 0; off >>= 1)
        s += __shfl_xor(s, off, 64);

    if (lane == 0)
        out[edge] = s + b[0];
}

extern "C" void kernel_launch(void* const* d_in, const int* in_sizes, int n_in,
                              void* d_out, int out_size, void* d_ws, size_t ws_size,
                              hipStream_t stream) {
    const float* nodes = (const float*)d_in[0];   // [N_NODES, 128] f32
    const int*   r_idx = (const int*)d_in[1];     // [E] int32
    const int*   c_idx = (const int*)d_in[2];     // [E] int32
    const float* w     = (const float*)d_in[3];   // [128, 1] f32
    const float* b     = (const float*)d_in[4];   // [1] f32
    float*       out   = (float*)d_out;           // [E] f32

    const int n_edges = in_sizes[1];

    const size_t part_bytes = (size_t)NSTRIPE * n_edges * sizeof(float); // 9.6MB

    if (ws_size >= part_bytes) {
        float* partial = (float*)d_ws;

        // pass 1: XCD-pinned stripe gather (pays the poison-drain tax)
        {
            const int chunks = (n_edges + EPB - 1) / EPB;   // 9375 at E=600k
            k_gather_stripe<<<chunks * NSTRIPE, 256, 0, stream>>>(
                nodes, r_idx, c_idx, w, partial, n_edges);
        }
        // pass 2: reduce partials (+bias)
        {
            const int quads = (n_edges + 3) / 4;
            const int grid  = (quads + 255) / 256;
            k_reduce<<<grid, 256, 0, stream>>>(partial, b, out, n_edges);
        }
    } else {
        const int block = 256;
        const int grid  = (int)(((long long)n_edges * 32 + block - 1) / block);
        gather_edges_f32<<<grid, block, 0, stream>>>(
            nodes, r_idx, c_idx, w, b, out, n_edges);
    }
}

// Round 11
// 131.531 us; speedup vs baseline: 3.4539x; 1.1618x over previous
//
#include <hip/hip_runtime.h>
#include <hip/hip_bf16.h>
#include <hip/hip_fp16.h>
#include <stdint.h>

// out[e] = sum_d |nodes[r[e]][d] - nodes[c[e]][d]| * w[d] + b[0]
// E = 600000, D = 128, N_OUT = 1.
//
// Machine model (fit R1-R12):
//   gather bound: ~0.74 L1-miss lane-requests/cy/CU, 16 B/request max.
//     fp16 full row = 19.2M requests -> 42 us (R2 measured 42.4: AT roofline).
//   fixed: 42 us ws-poison fill in dur_us; ~5-15 us per extra kernel.
//   R10: int8 absmax 0.0488 > 0.0481 threshold -> sub-16-bit table dead
//     (12-bit would pass numerically but only saves ~9 us; deferred).
//   R12: fp16 + NT-hinted convert FAILED absmax 2.52 — only never-proven
//     ingredient was nontemporal load/store builtins in convert. NT hints
//     in convert are hereby banned; all other parts have passing rounds.
// R13 (this): convert-cost experiment with PROVEN parts only:
//   - gather: R3's gather_edges_f16_ilp VERBATIM (passed R3/R4, 0.0078).
//   - convert: R6's conv_item shape (16 floats/thread, grid-stride, plain
//     float4 loads / uint4 stores — R6 passed correctness), linear layout.
//   Pre-committed read: PASS + total 107-118 -> convert was attribution
//   artifact, roofline-fast. PASS + total ~128-131 -> convert structurally
//   ~40 us -> declare structural roofline next round.

#define D_FEAT 128

// ---- pass 1: fp32 -> fp16 table, 16 floats/thread, grid-stride ----
__global__ __launch_bounds__(256) void k_convert(
    const float* __restrict__ src, __half* __restrict__ dst, int n_items)
{
    const int stride = gridDim.x * blockDim.x;
    for (int i = blockIdx.x * blockDim.x + threadIdx.x; i < n_items;
         i += stride) {
        const float4* s = (const float4*)src + 4 * (size_t)i;
        const float4 a = s[0];
        const float4 b = s[1];
        const float4 c = s[2];
        const float4 d = s[3];

        uint4 p0, p1;
        ((__half2*)&p0)[0] = __floats2half2_rn(a.x, a.y);
        ((__half2*)&p0)[1] = __floats2half2_rn(a.z, a.w);
        ((__half2*)&p0)[2] = __floats2half2_rn(b.x, b.y);
        ((__half2*)&p0)[3] = __floats2half2_rn(b.z, b.w);
        ((__half2*)&p1)[0] = __floats2half2_rn(c.x, c.y);
        ((__half2*)&p1)[1] = __floats2half2_rn(c.z, c.w);
        ((__half2*)&p1)[2] = __floats2half2_rn(d.x, d.y);
        ((__half2*)&p1)[3] = __floats2half2_rn(d.z, d.w);

        uint4* o = (uint4*)dst + 2 * (size_t)i;
        o[0] = p0;
        o[1] = p1;
    }
}

// ---- pass 2: fp16 full-row gather — R3 kernel VERBATIM ----
// 8 lanes/edge. Row = 128 halves = 16 chunks of 16B. Lane l loads chunks l
// and l+8 of each endpoint -> 4 independent gather loads/thread; per wave
// instruction the 64 lanes cover one full 128B half-row of each of 8 rows.
__global__ __launch_bounds__(256) void gather_edges_f16_ilp(
    const __half* __restrict__ tbl,
    const int*   __restrict__ r_idx,
    const int*   __restrict__ c_idx,
    const float* __restrict__ w,
    const float* __restrict__ b,
    float*       __restrict__ out,
    int n_edges)
{
    const int tid  = blockIdx.x * blockDim.x + threadIdx.x;
    const int lane = tid & 7;
    const int edge = tid >> 3;
    if (edge >= n_edges) return;

    const int r = r_idx[edge];
    const int c = c_idx[edge];

    const float4* arow = (const float4*)(tbl + (size_t)r * D_FEAT);
    const float4* brow = (const float4*)(tbl + (size_t)c * D_FEAT);

    // 4 independent gather loads issued back-to-back:
    const float4 a0 = arow[lane];
    const float4 a1 = arow[lane + 8];
    const float4 b0 = brow[lane];
    const float4 b1 = brow[lane + 8];

    // w is 512 B, L1-resident broadcast. Chunk l -> w float4s {2l, 2l+1};
    // chunk l+8 -> {2l+16, 2l+17}.
    const float4 w00 = ((const float4*)w)[2 * lane + 0];
    const float4 w01 = ((const float4*)w)[2 * lane + 1];
    const float4 w10 = ((const float4*)w)[2 * lane + 16];
    const float4 w11 = ((const float4*)w)[2 * lane + 17];

    const __half2* a0h = (const __half2*)&a0;
    const __half2* b0h = (const __half2*)&b0;
    const __half2* a1h = (const __half2*)&a1;
    const __half2* b1h = (const __half2*)&b1;

    float s = 0.f;
    {
        const float2 x0 = __half22float2(a0h[0]), y0 = __half22float2(b0h[0]);
        const float2 x1 = __half22float2(a0h[1]), y1 = __half22float2(b0h[1]);
        const float2 x2 = __half22float2(a0h[2]), y2 = __half22float2(b0h[2]);
        const float2 x3 = __half22float2(a0h[3]), y3 = __half22float2(b0h[3]);
        s += fabsf(x0.x - y0.x) * w00.x + fabsf(x0.y - y0.y) * w00.y
           + fabsf(x1.x - y1.x) * w00.z + fabsf(x1.y - y1.y) * w00.w
           + fabsf(x2.x - y2.x) * w01.x + fabsf(x2.y - y2.y) * w01.y
           + fabsf(x3.x - y3.x) * w01.z + fabsf(x3.y - y3.y) * w01.w;
    }
    {
        const float2 x0 = __half22float2(a1h[0]), y0 = __half22float2(b1h[0]);
        const float2 x1 = __half22float2(a1h[1]), y1 = __half22float2(b1h[1]);
        const float2 x2 = __half22float2(a1h[2]), y2 = __half22float2(b1h[2]);
        const float2 x3 = __half22float2(a1h[3]), y3 = __half22float2(b1h[3]);
        s += fabsf(x0.x - y0.x) * w10.x + fabsf(x0.y - y0.y) * w10.y
           + fabsf(x1.x - y1.x) * w10.z + fabsf(x1.y - y1.y) * w10.w
           + fabsf(x2.x - y2.x) * w11.x + fabsf(x2.y - y2.y) * w11.y
           + fabsf(x3.x - y3.x) * w11.z + fabsf(x3.y - y3.y) * w11.w;
    }

    // Reduce across the 8-lane group (xor masks < 8 never cross groups).
    #pragma unroll
    for (int off = 4; off > 0; off >>= 1)
        s += __shfl_xor(s, off, 64);

    if (lane == 0)
        out[edge] = s + b[0];
}

// ---- last-resort: direct fp32 gather if ws too small ----
__global__ __launch_bounds__(256) void gather_edges_f32(
    const float* __restrict__ nodes,
    const int*   __restrict__ r_idx,
    const int*   __restrict__ c_idx,
    const float* __restrict__ w,
    const float* __restrict__ b,
    float*       __restrict__ out,
    int n_edges)
{
    const int tid  = blockIdx.x * blockDim.x + threadIdx.x;
    const int lane = tid & 31;
    const int edge = tid >> 5;
    if (edge >= n_edges) return;

    const int r = r_idx[edge];
    const int c = c_idx[edge];

    const float4 wv = ((const float4*)w)[lane];
    const float4 av = ((const float4*)(nodes + (size_t)r * D_FEAT))[lane];
    const float4 bv = ((const float4*)(nodes + (size_t)c * D_FEAT))[lane];

    float s = fabsf(av.x - bv.x) * wv.x
            + fabsf(av.y - bv.y) * wv.y
            + fabsf(av.z - bv.z) * wv.z
            + fabsf(av.w - bv.w) * wv.w;

    #pragma unroll
    for (int off = 16; off > 0; off >>= 1)
        s += __shfl_xor(s, off, 64);

    if (lane == 0)
        out[edge] = s + b[0];
}

extern "C" void kernel_launch(void* const* d_in, const int* in_sizes, int n_in,
                              void* d_out, int out_size, void* d_ws, size_t ws_size,
                              hipStream_t stream) {
    const float* nodes = (const float*)d_in[0];   // [N_NODES, 128] f32
    const int*   r_idx = (const int*)d_in[1];     // [E] int32
    const int*   c_idx = (const int*)d_in[2];     // [E] int32
    const float* w     = (const float*)d_in[3];   // [128, 1] f32
    const float* b     = (const float*)d_in[4];   // [1] f32
    float*       out   = (float*)d_out;           // [E] f32

    const int n_edges   = in_sizes[1];
    const int n_nodes_f = in_sizes[0];            // n_nodes * 128 floats
    const size_t tbl_bytes = (size_t)n_nodes_f * sizeof(__half);

    if (ws_size >= tbl_bytes && (n_nodes_f & 15) == 0) {
        __half* tbl = (__half*)d_ws;

        // pass 1: streaming convert (16 floats/thread, grid-stride, plain)
        {
            const int n_items = n_nodes_f / 16;   // 800k at N=100k
            const int grid    = 1024;
            k_convert<<<grid, 256, 0, stream>>>(nodes, tbl, n_items);
        }
        // pass 2: fp16 full-row gather (R3-proven), direct out
        {
            const long long threads = (long long)n_edges * 8;
            const int grid = (int)((threads + 255) / 256);
            gather_edges_f16_ilp<<<grid, 256, 0, stream>>>(
                tbl, r_idx, c_idx, w, b, out, n_edges);
        }
    } else {
        const int block = 256;
        const int grid  = (int)(((long long)n_edges * 32 + block - 1) / block);
        gather_edges_f32<<<grid, block, 0, stream>>>(
            nodes, r_idx, c_idx, w, b, out, n_edges);
    }
}